// Round 15
// baseline (144.259 us; speedup 1.0000x reference)
//
#include <hip/hip_runtime.h>

#define N_NODES 50000
#define N_EDGES 600000
#define D 128
#define BM 32
#define NT (2 * N_NODES)           // 100000 combined rows (in | out)
#define NE2 (2 * N_EDGES)          // 1200000 combined edges
#define NPAD 50048                 // 782 * 64
#define KA 384                     // A columns: x | agg_in | agg_out
#define GBM 64                     // gemm M-tile
#define NBB 1563                   // buckets of 64 combined rows
#define CAPB 2048                  // row_sort LDS capacity
#define CHUNK_A 4096               // scatter edges per block

typedef __attribute__((ext_vector_type(8))) short bf16x8;
typedef __attribute__((ext_vector_type(4))) float f32x4;

__device__ inline unsigned short bfr(float x) {          // f32 -> bf16 RNE
    unsigned b = __float_as_uint(x);
    b += 0x7FFFu + ((b >> 16) & 1u);
    return (unsigned short)(b >> 16);
}
__device__ inline float bf_lo(unsigned u) { return __uint_as_float(u << 16); }
__device__ inline float bf_hi(unsigned u) { return __uint_as_float(u & 0xFFFF0000u); }

// == prep: cvt_x + cvt_w + zero pad-agg + bucket hist (bcnt pre-zeroed) ==
#define G1 (NPAD * 32 / 256)       // 6256: x -> A[:,0:128] bf16
#define G2 192                     // 128*384/256: W -> Wc
#define NZI (48 * 128)             // pad-row agg ints
#define G3 ((NZI + 255) / 256)     // 24
#define G4H 64                     // hist blocks

__global__ __launch_bounds__(256) void prep(
    const float* __restrict__ x, const float* __restrict__ Ws,
    const float* __restrict__ Wi, const float* __restrict__ Wo,
    const int* __restrict__ ir, const int* __restrict__ orow,
    short* __restrict__ A, short* __restrict__ Wc, int* __restrict__ bcnt)
{
    __shared__ int h[NBB];
    const int bid = blockIdx.x, t = threadIdx.x;
    if (bid < G1) {
        int gid = bid * 256 + t;
        int row = gid >> 5, c4 = gid & 31;
        ushort4 o = {0, 0, 0, 0};
        if (row < N_NODES) {
            float4 v = *reinterpret_cast<const float4*>(x + (size_t)row * D + c4 * 4);
            o.x = bfr(v.x); o.y = bfr(v.y); o.z = bfr(v.z); o.w = bfr(v.w);
        }
        *reinterpret_cast<ushort4*>(A + (size_t)row * KA + c4 * 4) = o;
    } else if (bid < G1 + G2) {
        int gid = (bid - G1) * 256 + t;
        int j = gid / 384, k = gid - j * 384;
        float v = (k < 128) ? Ws[j * 128 + k]
                : (k < 256) ? Wi[j * 128 + k - 128]
                            : Wo[j * 128 + k - 256];
        Wc[j * KA + k] = (short)bfr(v);
    } else if (bid < G1 + G2 + G3) {
        int z = (bid - G1 - G2) * 256 + t;
        if (z < NZI) {
            int row = N_NODES + (z >> 7);
            int o = z & 127;
            ((int*)A)[(size_t)row * (KA / 2) + 64 + o] = 0;  // agg cols [128,384)
        }
    } else {
        // 64-row-bucket histogram, LDS-aggregated (bcnt zeroed by memset)
        for (int i = t; i < NBB; i += 256) h[i] = 0;
        __syncthreads();
        int bb = bid - (G1 + G2 + G3);
        for (int e = bb * 256 + t; e < NE2; e += G4H * 256) {
            int rid = (e < N_EDGES) ? ir[e] : N_NODES + orow[e - N_EDGES];
            atomicAdd(&h[rid >> 6], 1);
        }
        __syncthreads();
        for (int i = t; i < NBB; i += 256)
            if (h[i]) atomicAdd(&bcnt[i], h[i]);
    }
}

__global__ __launch_bounds__(1024) void scan_buckets(
    const int* __restrict__ bcnt, int* __restrict__ bbase, int* __restrict__ bcur)
{
    __shared__ int s[1024];
    const int t = threadIdx.x;
    const int i0 = 2 * t, i1 = 2 * t + 1;
    int v0 = (i0 < NBB) ? bcnt[i0] : 0;
    int v1 = (i1 < NBB) ? bcnt[i1] : 0;
    int v = v0 + v1;
    s[t] = v;
    __syncthreads();
    for (int o = 1; o < 1024; o <<= 1) {
        int u = (t >= o) ? s[t - o] : 0;
        __syncthreads();
        s[t] += u;
        __syncthreads();
    }
    int ex = s[t] - v;
    if (i0 < NBB) { bbase[i0] = ex;      bcur[i0] = ex; }
    if (i1 < NBB) { bbase[i1] = ex + v0; bcur[i1] = ex + v0; }
}

// Scatter: LDS counting-sort per 4096-edge chunk -> bucket-grouped pairp.
// pairp[pos] = { col | (rid&63)<<16 , val }
__global__ __launch_bounds__(1024) void scatter_chunks(
    const int* __restrict__ ir, const int* __restrict__ icol, const float* __restrict__ ival,
    const int* __restrict__ orow, const int* __restrict__ ocol, const float* __restrict__ oval,
    int* __restrict__ bcur, int2* __restrict__ pairp)
{
    __shared__ int2 pay[CHUNK_A];    // 32 KB
    __shared__ int  dstp[CHUNK_A];   // 16 KB
    __shared__ int  hist[NBB];
    __shared__ int  gb2[NBB];
    __shared__ int  sbuf[1024];

    const int t = threadIdx.x;
    for (int i = t; i < NBB; i += 1024) hist[i] = 0;
    __syncthreads();

    const int e0 = blockIdx.x * CHUNK_A;
    const int m = min(NE2 - e0, CHUNK_A);
    int bk4[4], px4[4], vv4[4];
#pragma unroll
    for (int i = 0; i < 4; ++i) {
        int e = e0 + t + i * 1024;
        int rid, col; float val;
        if (e < N_EDGES)      { rid = ir[e];                       col = icol[e];            val = ival[e]; }
        else if (e < NE2)     { rid = N_NODES + orow[e - N_EDGES]; col = ocol[e - N_EDGES];  val = oval[e - N_EDGES]; }
        else                  { rid = -1; col = 0; val = 0.f; }
        if (rid >= 0) {
            bk4[i] = rid >> 6;
            px4[i] = (col & 0xFFFF) | ((rid & 63) << 16);
            vv4[i] = __float_as_int(val);
            atomicAdd(&hist[bk4[i]], 1);
        } else bk4[i] = -1;
    }
    __syncthreads();

    const int i0 = 2 * t, i1 = 2 * t + 1;
    int v0 = (i0 < NBB) ? hist[i0] : 0;
    int v1 = (i1 < NBB) ? hist[i1] : 0;
    int v = v0 + v1;
    sbuf[t] = v;
    __syncthreads();
    for (int o = 1; o < 1024; o <<= 1) {
        int u = (t >= o) ? sbuf[t - o] : 0;
        __syncthreads();
        sbuf[t] += u;
        __syncthreads();
    }
    int ex = sbuf[t] - v;
    if (i0 < NBB) {
        int g = v0 ? atomicAdd(&bcur[i0], v0) : 0;
        gb2[i0] = g - ex;
        hist[i0] = ex;
    }
    if (i1 < NBB) {
        int g = v1 ? atomicAdd(&bcur[i1], v1) : 0;
        gb2[i1] = g - (ex + v0);
        hist[i1] = ex + v0;
    }
    __syncthreads();

#pragma unroll
    for (int i = 0; i < 4; ++i) {
        if (bk4[i] < 0) continue;
        int s = atomicAdd(&hist[bk4[i]], 1);
        pay[s]  = make_int2(px4[i], vv4[i]);
        dstp[s] = gb2[bk4[i]] + s;
    }
    __syncthreads();

    for (int i = t; i < m; i += 1024)
        pairp[dstp[i]] = pay[i];
}

// row_sort: one block per 64-row bucket; counting-sort run by row-in-bucket,
// emit row-sorted 4B-packed pairp2 { bf16(val)<<16 | col } + global row_ptr.
__global__ __launch_bounds__(256) void row_sort(
    const int* __restrict__ bbase, const int* __restrict__ bcnt,
    const int2* __restrict__ pairp, unsigned* __restrict__ pairp2,
    int* __restrict__ row_ptr)
{
    __shared__ int2 pay[CAPB];       // 16 KB
    __shared__ int  rs[64];
    __shared__ int  rcur[64];

    const int b = blockIdx.x, t = threadIdx.x;
    const int base = bbase[b];
    const int n = bcnt[b];

    if (t < 64) rs[t] = 0;
    __syncthreads();

    const bool fast = (n <= CAPB);
    if (fast) {
        for (int i = t; i < n; i += 256) {
            int2 p = pairp[base + i];
            pay[i] = p;
            atomicAdd(&rs[(p.x >> 16) & 63], 1);
        }
    } else {
        for (int i = t; i < n; i += 256)
            atomicAdd(&rs[(pairp[base + i].x >> 16) & 63], 1);
    }
    __syncthreads();

    if (t < 64) {
        int v = rs[t];
        int a = v;
#pragma unroll
        for (int o = 1; o < 64; o <<= 1) {
            int u = __shfl_up(a, o);
            if (t >= o) a += u;
        }
        int ex = a - v;
        rcur[t] = ex;
        row_ptr[b * 64 + t] = base + ex;        // bucket 1562's row 32 -> row_ptr[NT]=NE2
    }
    __syncthreads();

    if (fast) {
        for (int i = t; i < n; i += 256) {
            int2 p = pay[i];
            int pos = atomicAdd(&rcur[(p.x >> 16) & 63], 1);
            pairp2[base + pos] = ((unsigned)bfr(__int_as_float(p.y)) << 16)
                               | (unsigned)(p.x & 0xFFFF);
        }
    } else {
        for (int i = t; i < n; i += 256) {
            int2 p = pairp[base + i];
            int pos = atomicAdd(&rcur[(p.x >> 16) & 63], 1);
            pairp2[base + pos] = ((unsigned)bfr(__int_as_float(p.y)) << 16)
                               | (unsigned)(p.x & 0xFFFF);
        }
    }
}

// gather: one wave per combined row; barrier-free, LDS-free.
// 4B edge records wave-uniform -> scalar loads; 8 x-loads in flight.
__global__ __launch_bounds__(256) void gather_rows(
    const int* __restrict__ row_ptr, const unsigned* __restrict__ pairp2,
    short* __restrict__ A)
{
    const int wv = blockIdx.x * 4 + (threadIdx.x >> 6);
    if (wv >= NT) return;
    const int lane = threadIdx.x & 63;
    int s = row_ptr[wv];
    int e = row_ptr[wv + 1];
    s = __builtin_amdgcn_readfirstlane(s);
    e = __builtin_amdgcn_readfirstlane(e);

    const char* Ab = (const char*)A + lane * 4;
    float ax = 0.f, ay = 0.f;

    for (int i = s; i < e; i += 8) {
#pragma unroll
        for (int k = 0; k < 8; ++k) {
            int idx = i + k;
            unsigned p = pairp2[min(idx, e - 1)];
            float v = (idx < e) ? bf_hi(p) : 0.f;
            unsigned u = *(const unsigned*)(Ab + (unsigned)((p & 0xFFFF) * (KA * 2)));
            ax += v * bf_lo(u);
            ay += v * bf_hi(u);
        }
    }

    unsigned o = ((unsigned)bfr(ay) << 16) | (unsigned)bfr(ax);
    size_t dst = (wv < N_NODES)
               ? ((size_t)wv * (KA * 2) + 256 + lane * 4)
               : ((size_t)(wv - N_NODES) * (KA * 2) + 512 + lane * 4);
    *(unsigned*)((char*)A + dst) = o;
}

// ================= MFMA GEMM + bias + LayerNorm + ReLU =================
// A-tile staging via global_load_lds (16B/lane): LDS dest linear (wave-uniform
// base + lane*16), XOR swizzle folded into per-lane GLOBAL source address.
__global__ __launch_bounds__(512) void gemm_mfma(
    const short* __restrict__ A, const short* __restrict__ Wc,
    const float* __restrict__ b, const float* __restrict__ gamma,
    const float* __restrict__ beta, float* __restrict__ out)
{
    __shared__ short Alds[GBM * KA];     // 48 KB
    __shared__ float red[8][64][2];      // 4 KB
    __shared__ float2 mustd[64];

    const int t = threadIdx.x;
    const int l = t & 63, w = t >> 6;
    const int q = l >> 4, c = l & 15;
    const int base = blockIdx.x * GBM;

    bf16x8 bfrag[12];
    const short* wrow = Wc + (size_t)(w * 16 + c) * KA + q * 8;
#pragma unroll
    for (int s = 0; s < 12; ++s)
        bfrag[s] = *reinterpret_cast<const bf16x8*>(wrow + s * 32);

    // async stage: slot = t + i*512; lds byte = slot*16 (linear);
    // global src = A[(base+row)*KA + (j ^ (row&7))*8], row=slot/48, j=slot%48
    const short* Ag = A + (size_t)base * KA;
#pragma unroll
    for (int i = 0; i < 6; ++i) {
        int slot = t + i * 512;
        int row = slot / 48, j = slot % 48;
        const short* src = Ag + row * KA + (j ^ (row & 7)) * 8;
        int wbase = (i * 512 + (t & ~63)) * 16;   // wave-uniform LDS byte base
        __builtin_amdgcn_global_load_lds(
            (const __attribute__((address_space(1))) void*)src,
            (__attribute__((address_space(3))) void*)((char*)Alds + wbase),
            16, 0, 0);
    }
    __syncthreads();

    f32x4 acc[4];
#pragma unroll
    for (int rg = 0; rg < 4; ++rg) acc[rg] = (f32x4){0.f, 0.f, 0.f, 0.f};

#pragma unroll
    for (int s = 0; s < 12; ++s) {
#pragma unroll
        for (int rg = 0; rg < 4; ++rg) {
            int row = rg * 16 + c;
            int c16 = (s * 4 + q) ^ (row & 7);
            bf16x8 af = *reinterpret_cast<const bf16x8*>(&Alds[row * KA + c16 * 8]);
            acc[rg] = __builtin_amdgcn_mfma_f32_16x16x32_bf16(af, bfrag[s], acc[rg], 0, 0, 0);
        }
    }

    const float bj = b[w * 16 + c];
    const float gj = gamma[w * 16 + c];
    const float ej = beta[w * 16 + c];

#pragma unroll
    for (int rg = 0; rg < 4; ++rg) {
#pragma unroll
        for (int r = 0; r < 4; ++r) {
            float hv = acc[rg][r] + bj;
            acc[rg][r] = hv;
            float s1 = hv, s2 = hv * hv;
#pragma unroll
            for (int m = 1; m < 16; m <<= 1) {
                s1 += __shfl_xor(s1, m);
                s2 += __shfl_xor(s2, m);
            }
            if (c == 0) {
                int row = rg * 16 + q * 4 + r;
                red[w][row][0] = s1;
                red[w][row][1] = s2;
            }
        }
    }
    __syncthreads();

    if (t < 64) {
        float s1 = 0.f, s2 = 0.f;
#pragma unroll
        for (int ww = 0; ww < 8; ++ww) { s1 += red[ww][t][0]; s2 += red[ww][t][1]; }
        float mu = s1 * (1.f / 128.f);
        float var = s2 * (1.f / 128.f) - mu * mu;
        mustd[t] = make_float2(mu, rsqrtf(var + 1e-5f));
    }
    __syncthreads();

#pragma unroll
    for (int rg = 0; rg < 4; ++rg) {
        int row0 = rg * 16 + q * 4;
        int node0 = base + row0;
#pragma unroll
        for (int r = 0; r < 4; ++r) {
            float2 ms = mustd[row0 + r];
            float y = (acc[rg][r] - ms.x) * ms.y * gj + ej;
            y = fmaxf(y, 0.f);
            if (node0 + r < N_NODES)
                out[(size_t)(node0 + r) * D + w * 16 + c] = y;
        }
    }
}

// ================= fp32 fallback (small ws) =================
__global__ __launch_bounds__(256) void spmm_scatter(
    const int* __restrict__ rows, const int* __restrict__ cols,
    const float* __restrict__ vals, const float* __restrict__ x,
    float* __restrict__ agg, int nE)
{
    int g = blockIdx.x * 256 + threadIdx.x;
    int e = g >> 5;
    if (e >= nE) return;
    int q = g & 31;
    int r = rows[e], c = cols[e];
    float v = vals[e];
    float4 xv = *reinterpret_cast<const float4*>(x + (size_t)c * D + (size_t)q * 4);
    float* ap = agg + (size_t)r * D + (size_t)q * 4;
    atomicAdd(ap + 0, v * xv.x);
    atomicAdd(ap + 1, v * xv.y);
    atomicAdd(ap + 2, v * xv.z);
    atomicAdd(ap + 3, v * xv.w);
}

__global__ __launch_bounds__(256) void gemm_ln_relu(
    const float* __restrict__ x, const float* __restrict__ agg_in,
    const float* __restrict__ agg_out,
    const float* __restrict__ Ws, const float* __restrict__ Wi,
    const float* __restrict__ Wo, const float* __restrict__ b,
    const float* __restrict__ gamma, const float* __restrict__ beta,
    float* __restrict__ out, int n)
{
    __shared__ float4 Wl[D * (D / 4)];
    __shared__ float4 Xl[BM * (D / 4)];

    const int t = threadIdx.x;
    const int l = t & 63;
    const int w = t >> 6;
    const int base = blockIdx.x * BM;
    const int j0 = l, j1 = l + 64;

    float acc0[8], acc1[8];
    const float bj0 = b[j0], bj1 = b[j1];
#pragma unroll
    for (int i = 0; i < 8; ++i) { acc0[i] = bj0; acc1[i] = bj1; }

    const float* srcs[3] = { x, agg_in, agg_out };
    const float* wms[3]  = { Ws, Wi, Wo };

#pragma unroll
    for (int s = 0; s < 3; ++s) {
        const float4* src4 = reinterpret_cast<const float4*>(srcs[s]);
        const float4* w4   = reinterpret_cast<const float4*>(wms[s]);
        __syncthreads();
#pragma unroll
        for (int it = 0; it < 16; ++it) {
            int gi = t + 256 * it;
            int j = gi >> 5, k4 = gi & 31;
            Wl[j * 32 + (k4 ^ (j & 7))] = w4[gi];
        }
#pragma unroll
        for (int it = 0; it < 4; ++it) {
            int gi = t + 256 * it;
            int m = gi >> 5, k4 = gi & 31;
            int node = base + m;
            float4 v = (node < n) ? src4[(size_t)node * 32 + k4]
                                  : make_float4(0.f, 0.f, 0.f, 0.f);
            Xl[m * 32 + k4] = v;
        }
        __syncthreads();

        const int sw = j0 & 7;
#pragma unroll 8
        for (int k4 = 0; k4 < 32; ++k4) {
            float4 w0 = Wl[j0 * 32 + (k4 ^ sw)];
            float4 w1 = Wl[j1 * 32 + (k4 ^ sw)];
#pragma unroll
            for (int i = 0; i < 8; ++i) {
                float4 xv = Xl[(w + 4 * i) * 32 + k4];
                acc0[i] += xv.x * w0.x + xv.y * w0.y + xv.z * w0.z + xv.w * w0.w;
                acc1[i] += xv.x * w1.x + xv.y * w1.y + xv.z * w1.z + xv.w * w1.w;
            }
        }
    }

    const float g0 = gamma[j0], g1 = gamma[j1];
    const float be0 = beta[j0], be1 = beta[j1];
#pragma unroll
    for (int i = 0; i < 8; ++i) {
        int node = base + w + 4 * i;
        float s  = acc0[i] + acc1[i];
        float ss = acc0[i] * acc0[i] + acc1[i] * acc1[i];
#pragma unroll
        for (int off = 32; off; off >>= 1) {
            s  += __shfl_xor(s, off);
            ss += __shfl_xor(ss, off);
        }
        float mu   = s * (1.0f / D);
        float var  = ss * (1.0f / D) - mu * mu;
        float rstd = rsqrtf(var + 1e-5f);
        if (node < n) {
            float y0 = (acc0[i] - mu) * rstd * g0 + be0;
            float y1 = (acc1[i] - mu) * rstd * g1 + be1;
            out[(size_t)node * D + j0] = fmaxf(y0, 0.f);
            out[(size_t)node * D + j1] = fmaxf(y1, 0.f);
        }
    }
}

extern "C" void kernel_launch(void* const* d_in, const int* in_sizes, int n_in,
                              void* d_out, int out_size, void* d_ws, size_t ws_size,
                              hipStream_t stream) {
    const float* x     = (const float*)d_in[0];
    const int*   ir    = (const int*)  d_in[1];
    const int*   icoln = (const int*)  d_in[2];
    const float* ival  = (const float*)d_in[3];
    const int*   orow  = (const int*)  d_in[4];
    const int*   ocol  = (const int*)  d_in[5];
    const float* oval  = (const float*)d_in[6];
    const float* Ws    = (const float*)d_in[7];
    const float* b     = (const float*)d_in[8];
    const float* Wi    = (const float*)d_in[9];
    const float* Wo    = (const float*)d_in[10];
    const float* gamma = (const float*)d_in[11];
    const float* beta  = (const float*)d_in[12];
    float* out = (float*)d_out;

    // workspace layout
    short*    A       = (short*)d_ws;                      // NPAD x 384 bf16
    short*    Wc      = A + (size_t)NPAD * KA;             // 128 x 384 bf16
    int*      bcnt    = (int*)(Wc + (size_t)128 * KA);
    int*      bbase   = bcnt + NBB;
    int*      bcur    = bbase + NBB;
    int*      row_ptr = bcur + NBB;                        // NBB*64 + 1 entries
    uintptr_t pp      = (uintptr_t)(row_ptr + NBB * 64 + 1);
    pp = (pp + 7) & ~(uintptr_t)7;
    int2*     pairp   = (int2*)pp;                         // NE2 (8B)
    unsigned* pairp2  = (unsigned*)(pairp + NE2);          // NE2 (4B packed)
    size_t need = (size_t)((char*)(pairp2 + NE2) - (char*)d_ws);

    if (ws_size >= need) {
        hipMemsetAsync(bcnt, 0, NBB * sizeof(int), stream);
        prep<<<G1 + G2 + G3 + G4H, 256, 0, stream>>>(
            x, Ws, Wi, Wo, ir, orow, A, Wc, bcnt);
        scan_buckets<<<1, 1024, 0, stream>>>(bcnt, bbase, bcur);
        scatter_chunks<<<(NE2 + CHUNK_A - 1) / CHUNK_A, 1024, 0, stream>>>(
            ir, icoln, ival, orow, ocol, oval, bcur, pairp);
        row_sort<<<NBB, 256, 0, stream>>>(bbase, bcnt, pairp, pairp2, row_ptr);
        gather_rows<<<(NT + 3) / 4, 256, 0, stream>>>(row_ptr, pairp2, A);
        gemm_mfma<<<NPAD / GBM, 512, 0, stream>>>(A, Wc, b, gamma, beta, out);
    } else {
        float* agg_in  = (float*)d_ws;
        float* agg_out = agg_in + (size_t)N_NODES * D;
        hipMemsetAsync(d_ws, 0, 2 * (size_t)N_NODES * D * sizeof(float), stream);
        const int eblocks = (N_EDGES * 32 + 255) / 256;
        spmm_scatter<<<eblocks, 256, 0, stream>>>(ir, icoln, ival, x, agg_in, N_EDGES);
        spmm_scatter<<<eblocks, 256, 0, stream>>>(orow, ocol, oval, x, agg_out, N_EDGES);
        const int gblocks = (N_NODES + BM - 1) / BM;
        gemm_ln_relu<<<gblocks, 256, 0, stream>>>(x, agg_in, agg_out, Ws, Wi, Wo,
                                                  b, gamma, beta, out, N_NODES);
    }
}

// Round 16
// 118.890 us; speedup vs baseline: 1.2134x; 1.2134x over previous
//
#include <hip/hip_runtime.h>

#define N_NODES 50000
#define N_EDGES 600000
#define D 128
#define BM 32
#define NT (2 * N_NODES)           // 100000 combined rows (in | out)
#define NE2 (2 * N_EDGES)          // 1200000 combined edges
#define NPAD 50048                 // 782 * 64
#define KA 384                     // A columns: x | agg_in | agg_out
#define GBM 64                     // gemm M-tile
#define NBB 1563                   // buckets of 64 combined rows
#define CAPB 2048                  // row_sort LDS capacity
#define CHUNK_A 4096               // scatter edges per block

typedef __attribute__((ext_vector_type(8))) short bf16x8;
typedef __attribute__((ext_vector_type(4))) float f32x4;

__device__ inline unsigned short bfr(float x) {          // f32 -> bf16 RNE
    unsigned b = __float_as_uint(x);
    b += 0x7FFFu + ((b >> 16) & 1u);
    return (unsigned short)(b >> 16);
}
__device__ inline float bf_lo(unsigned u) { return __uint_as_float(u << 16); }
__device__ inline float bf_hi(unsigned u) { return __uint_as_float(u & 0xFFFF0000u); }

// ============ prep: cvt_x + cvt_w + zero(bcnt, pad agg rows) ============
#define G1 (NPAD * 32 / 256)       // 6256
#define G2 192                     // 128*384/256
#define NZI (NBB + 48 * 128)       // zero-ints: bcnt + pad agg region
#define G3 ((NZI + 255) / 256)     // 31

__global__ __launch_bounds__(256) void prep(
    const float* __restrict__ x, const float* __restrict__ Ws,
    const float* __restrict__ Wi, const float* __restrict__ Wo,
    short* __restrict__ A, short* __restrict__ Wc, int* __restrict__ bcnt)
{
    const int bid = blockIdx.x, t = threadIdx.x;
    if (bid < G1) {
        int gid = bid * 256 + t;
        int row = gid >> 5, c4 = gid & 31;
        ushort4 o = {0, 0, 0, 0};
        if (row < N_NODES) {
            float4 v = *reinterpret_cast<const float4*>(x + (size_t)row * D + c4 * 4);
            o.x = bfr(v.x); o.y = bfr(v.y); o.z = bfr(v.z); o.w = bfr(v.w);
        }
        *reinterpret_cast<ushort4*>(A + (size_t)row * KA + c4 * 4) = o;
    } else if (bid < G1 + G2) {
        int gid = (bid - G1) * 256 + t;
        int j = gid / 384, k = gid - j * 384;
        float v = (k < 128) ? Ws[j * 128 + k]
                : (k < 256) ? Wi[j * 128 + k - 128]
                            : Wo[j * 128 + k - 256];
        Wc[j * KA + k] = (short)bfr(v);
    } else {
        int z = (bid - G1 - G2) * 256 + t;
        if (z < NBB) bcnt[z] = 0;
        else if (z < NZI) {
            int z2 = z - NBB;
            int row = N_NODES + (z2 >> 7);
            int o = z2 & 127;
            ((int*)A)[(size_t)row * (KA / 2) + 64 + o] = 0;  // agg cols [128,384)
        }
    }
}

// ================= bucket CSR build (64-row buckets) =================

__global__ __launch_bounds__(1024) void bucket_hist(
    const int* __restrict__ ir, const int* __restrict__ orow, int* __restrict__ bcnt)
{
    __shared__ int h[NBB];
    for (int i = threadIdx.x; i < NBB; i += 1024) h[i] = 0;
    __syncthreads();
    int stride = gridDim.x * 1024;
    for (int e = blockIdx.x * 1024 + threadIdx.x; e < NE2; e += stride) {
        int rid = (e < N_EDGES) ? ir[e] : N_NODES + orow[e - N_EDGES];
        atomicAdd(&h[rid >> 6], 1);
    }
    __syncthreads();
    for (int i = threadIdx.x; i < NBB; i += 1024)
        if (h[i]) atomicAdd(&bcnt[i], h[i]);
}

__global__ __launch_bounds__(1024) void scan_buckets(
    const int* __restrict__ bcnt, int* __restrict__ bbase, int* __restrict__ bcur)
{
    __shared__ int s[1024];
    const int t = threadIdx.x;
    const int i0 = 2 * t, i1 = 2 * t + 1;
    int v0 = (i0 < NBB) ? bcnt[i0] : 0;
    int v1 = (i1 < NBB) ? bcnt[i1] : 0;
    int v = v0 + v1;
    s[t] = v;
    __syncthreads();
    for (int o = 1; o < 1024; o <<= 1) {
        int u = (t >= o) ? s[t - o] : 0;
        __syncthreads();
        s[t] += u;
        __syncthreads();
    }
    int ex = s[t] - v;
    if (i0 < NBB) { bbase[i0] = ex;      bcur[i0] = ex; }
    if (i1 < NBB) { bbase[i1] = ex + v0; bcur[i1] = ex + v0; }
}

// Scatter: LDS counting-sort per 4096-edge chunk -> bucket-grouped pairp.
// pairp[pos] = { col | (rid&63)<<16 , val }
__global__ __launch_bounds__(1024) void scatter_chunks(
    const int* __restrict__ ir, const int* __restrict__ icol, const float* __restrict__ ival,
    const int* __restrict__ orow, const int* __restrict__ ocol, const float* __restrict__ oval,
    int* __restrict__ bcur, int2* __restrict__ pairp)
{
    __shared__ int2 pay[CHUNK_A];    // 32 KB
    __shared__ int  dstp[CHUNK_A];   // 16 KB
    __shared__ int  hist[NBB];
    __shared__ int  gb2[NBB];
    __shared__ int  sbuf[1024];

    const int t = threadIdx.x;
    for (int i = t; i < NBB; i += 1024) hist[i] = 0;
    __syncthreads();

    const int e0 = blockIdx.x * CHUNK_A;
    const int m = min(NE2 - e0, CHUNK_A);
    int bk4[4], px4[4], vv4[4];
#pragma unroll
    for (int i = 0; i < 4; ++i) {
        int e = e0 + t + i * 1024;
        int rid, col; float val;
        if (e < N_EDGES)      { rid = ir[e];                       col = icol[e];            val = ival[e]; }
        else if (e < NE2)     { rid = N_NODES + orow[e - N_EDGES]; col = ocol[e - N_EDGES];  val = oval[e - N_EDGES]; }
        else                  { rid = -1; col = 0; val = 0.f; }
        if (rid >= 0) {
            bk4[i] = rid >> 6;
            px4[i] = (col & 0xFFFF) | ((rid & 63) << 16);
            vv4[i] = __float_as_int(val);
            atomicAdd(&hist[bk4[i]], 1);
        } else bk4[i] = -1;
    }
    __syncthreads();

    const int i0 = 2 * t, i1 = 2 * t + 1;
    int v0 = (i0 < NBB) ? hist[i0] : 0;
    int v1 = (i1 < NBB) ? hist[i1] : 0;
    int v = v0 + v1;
    sbuf[t] = v;
    __syncthreads();
    for (int o = 1; o < 1024; o <<= 1) {
        int u = (t >= o) ? sbuf[t - o] : 0;
        __syncthreads();
        sbuf[t] += u;
        __syncthreads();
    }
    int ex = sbuf[t] - v;
    if (i0 < NBB) {
        int g = v0 ? atomicAdd(&bcur[i0], v0) : 0;
        gb2[i0] = g - ex;
        hist[i0] = ex;
    }
    if (i1 < NBB) {
        int g = v1 ? atomicAdd(&bcur[i1], v1) : 0;
        gb2[i1] = g - (ex + v0);
        hist[i1] = ex + v0;
    }
    __syncthreads();

#pragma unroll
    for (int i = 0; i < 4; ++i) {
        if (bk4[i] < 0) continue;
        int s = atomicAdd(&hist[bk4[i]], 1);
        pay[s]  = make_int2(px4[i], vv4[i]);
        dstp[s] = gb2[bk4[i]] + s;
    }
    __syncthreads();

    for (int i = t; i < m; i += 1024)
        pairp[dstp[i]] = pay[i];
}

// row_sort: one block per 64-row bucket; counting-sort run by row-in-bucket,
// emit row-sorted 4B-packed pairp2 { bf16(val)<<16 | col } + global row_ptr.
__global__ __launch_bounds__(256) void row_sort(
    const int* __restrict__ bbase, const int* __restrict__ bcnt,
    const int2* __restrict__ pairp, unsigned* __restrict__ pairp2,
    int* __restrict__ row_ptr)
{
    __shared__ int2 pay[CAPB];       // 16 KB
    __shared__ int  rs[64];
    __shared__ int  rcur[64];

    const int b = blockIdx.x, t = threadIdx.x;
    const int base = bbase[b];
    const int n = bcnt[b];

    if (t < 64) rs[t] = 0;
    __syncthreads();

    const bool fast = (n <= CAPB);
    if (fast) {
        for (int i = t; i < n; i += 256) {
            int2 p = pairp[base + i];
            pay[i] = p;
            atomicAdd(&rs[(p.x >> 16) & 63], 1);
        }
    } else {
        for (int i = t; i < n; i += 256)
            atomicAdd(&rs[(pairp[base + i].x >> 16) & 63], 1);
    }
    __syncthreads();

    if (t < 64) {
        int v = rs[t];
        int a = v;
#pragma unroll
        for (int o = 1; o < 64; o <<= 1) {
            int u = __shfl_up(a, o);
            if (t >= o) a += u;
        }
        int ex = a - v;
        rcur[t] = ex;
        row_ptr[b * 64 + t] = base + ex;        // bucket 1562's row 32 -> row_ptr[NT]=NE2
    }
    __syncthreads();

    if (fast) {
        for (int i = t; i < n; i += 256) {
            int2 p = pay[i];
            int pos = atomicAdd(&rcur[(p.x >> 16) & 63], 1);
            pairp2[base + pos] = ((unsigned)bfr(__int_as_float(p.y)) << 16)
                               | (unsigned)(p.x & 0xFFFF);
        }
    } else {
        for (int i = t; i < n; i += 256) {
            int2 p = pairp[base + i];
            int pos = atomicAdd(&rcur[(p.x >> 16) & 63], 1);
            pairp2[base + pos] = ((unsigned)bfr(__int_as_float(p.y)) << 16)
                               | (unsigned)(p.x & 0xFFFF);
        }
    }
}

// gather: one wave per combined row; barrier-free, LDS-free.
// 4B edge records wave-uniform -> scalar loads; 8 x-loads in flight.
__global__ __launch_bounds__(256) void gather_rows(
    const int* __restrict__ row_ptr, const unsigned* __restrict__ pairp2,
    short* __restrict__ A)
{
    const int wv = blockIdx.x * 4 + (threadIdx.x >> 6);
    if (wv >= NT) return;
    const int lane = threadIdx.x & 63;
    int s = row_ptr[wv];
    int e = row_ptr[wv + 1];
    s = __builtin_amdgcn_readfirstlane(s);
    e = __builtin_amdgcn_readfirstlane(e);

    const char* Ab = (const char*)A + lane * 4;
    float ax = 0.f, ay = 0.f;

    for (int i = s; i < e; i += 8) {
#pragma unroll
        for (int k = 0; k < 8; ++k) {
            int idx = i + k;
            unsigned p = pairp2[min(idx, e - 1)];
            float v = (idx < e) ? bf_hi(p) : 0.f;
            unsigned u = *(const unsigned*)(Ab + (unsigned)((p & 0xFFFF) * (KA * 2)));
            ax += v * bf_lo(u);
            ay += v * bf_hi(u);
        }
    }

    unsigned o = ((unsigned)bfr(ay) << 16) | (unsigned)bfr(ax);
    size_t dst = (wv < N_NODES)
               ? ((size_t)wv * (KA * 2) + 256 + lane * 4)
               : ((size_t)(wv - N_NODES) * (KA * 2) + 512 + lane * 4);
    *(unsigned*)((char*)A + dst) = o;
}

// ================= MFMA GEMM + bias + LayerNorm + ReLU =================
// A-tile staging via global_load_lds (16B/lane): LDS dest linear (wave-uniform
// base + lane*16), XOR swizzle folded into per-lane GLOBAL source address.
__global__ __launch_bounds__(512) void gemm_mfma(
    const short* __restrict__ A, const short* __restrict__ Wc,
    const float* __restrict__ b, const float* __restrict__ gamma,
    const float* __restrict__ beta, float* __restrict__ out)
{
    __shared__ short Alds[GBM * KA];     // 48 KB
    __shared__ float red[8][64][2];      // 4 KB
    __shared__ float2 mustd[64];

    const int t = threadIdx.x;
    const int l = t & 63, w = t >> 6;
    const int q = l >> 4, c = l & 15;
    const int base = blockIdx.x * GBM;

    bf16x8 bfrag[12];
    const short* wrow = Wc + (size_t)(w * 16 + c) * KA + q * 8;
#pragma unroll
    for (int s = 0; s < 12; ++s)
        bfrag[s] = *reinterpret_cast<const bf16x8*>(wrow + s * 32);

    // async stage: slot = t + i*512; lds byte = slot*16 (linear);
    // global src = A[(base+row)*KA + (j ^ (row&7))*8], row=slot/48, j=slot%48
    const short* Ag = A + (size_t)base * KA;
#pragma unroll
    for (int i = 0; i < 6; ++i) {
        int slot = t + i * 512;
        int row = slot / 48, j = slot % 48;
        const short* src = Ag + row * KA + (j ^ (row & 7)) * 8;
        int wbase = (i * 512 + (t & ~63)) * 16;   // wave-uniform LDS byte base
        __builtin_amdgcn_global_load_lds(
            (const __attribute__((address_space(1))) void*)src,
            (__attribute__((address_space(3))) void*)((char*)Alds + wbase),
            16, 0, 0);
    }
    __syncthreads();

    f32x4 acc[4];
#pragma unroll
    for (int rg = 0; rg < 4; ++rg) acc[rg] = (f32x4){0.f, 0.f, 0.f, 0.f};

#pragma unroll
    for (int s = 0; s < 12; ++s) {
#pragma unroll
        for (int rg = 0; rg < 4; ++rg) {
            int row = rg * 16 + c;
            int c16 = (s * 4 + q) ^ (row & 7);
            bf16x8 af = *reinterpret_cast<const bf16x8*>(&Alds[row * KA + c16 * 8]);
            acc[rg] = __builtin_amdgcn_mfma_f32_16x16x32_bf16(af, bfrag[s], acc[rg], 0, 0, 0);
        }
    }

    const float bj = b[w * 16 + c];
    const float gj = gamma[w * 16 + c];
    const float ej = beta[w * 16 + c];

#pragma unroll
    for (int rg = 0; rg < 4; ++rg) {
#pragma unroll
        for (int r = 0; r < 4; ++r) {
            float hv = acc[rg][r] + bj;
            acc[rg][r] = hv;
            float s1 = hv, s2 = hv * hv;
#pragma unroll
            for (int m = 1; m < 16; m <<= 1) {
                s1 += __shfl_xor(s1, m);
                s2 += __shfl_xor(s2, m);
            }
            if (c == 0) {
                int row = rg * 16 + q * 4 + r;
                red[w][row][0] = s1;
                red[w][row][1] = s2;
            }
        }
    }
    __syncthreads();

    if (t < 64) {
        float s1 = 0.f, s2 = 0.f;
#pragma unroll
        for (int ww = 0; ww < 8; ++ww) { s1 += red[ww][t][0]; s2 += red[ww][t][1]; }
        float mu = s1 * (1.f / 128.f);
        float var = s2 * (1.f / 128.f) - mu * mu;
        mustd[t] = make_float2(mu, rsqrtf(var + 1e-5f));
    }
    __syncthreads();

#pragma unroll
    for (int rg = 0; rg < 4; ++rg) {
        int row0 = rg * 16 + q * 4;
        int node0 = base + row0;
#pragma unroll
        for (int r = 0; r < 4; ++r) {
            float2 ms = mustd[row0 + r];
            float y = (acc[rg][r] - ms.x) * ms.y * gj + ej;
            y = fmaxf(y, 0.f);
            if (node0 + r < N_NODES)
                out[(size_t)(node0 + r) * D + w * 16 + c] = y;
        }
    }
}

// ================= fp32 fallback (small ws) =================
__global__ __launch_bounds__(256) void spmm_scatter(
    const int* __restrict__ rows, const int* __restrict__ cols,
    const float* __restrict__ vals, const float* __restrict__ x,
    float* __restrict__ agg, int nE)
{
    int g = blockIdx.x * 256 + threadIdx.x;
    int e = g >> 5;
    if (e >= nE) return;
    int q = g & 31;
    int r = rows[e], c = cols[e];
    float v = vals[e];
    float4 xv = *reinterpret_cast<const float4*>(x + (size_t)c * D + (size_t)q * 4);
    float* ap = agg + (size_t)r * D + (size_t)q * 4;
    atomicAdd(ap + 0, v * xv.x);
    atomicAdd(ap + 1, v * xv.y);
    atomicAdd(ap + 2, v * xv.z);
    atomicAdd(ap + 3, v * xv.w);
}

__global__ __launch_bounds__(256) void gemm_ln_relu(
    const float* __restrict__ x, const float* __restrict__ agg_in,
    const float* __restrict__ agg_out,
    const float* __restrict__ Ws, const float* __restrict__ Wi,
    const float* __restrict__ Wo, const float* __restrict__ b,
    const float* __restrict__ gamma, const float* __restrict__ beta,
    float* __restrict__ out, int n)
{
    __shared__ float4 Wl[D * (D / 4)];
    __shared__ float4 Xl[BM * (D / 4)];

    const int t = threadIdx.x;
    const int l = t & 63;
    const int w = t >> 6;
    const int base = blockIdx.x * BM;
    const int j0 = l, j1 = l + 64;

    float acc0[8], acc1[8];
    const float bj0 = b[j0], bj1 = b[j1];
#pragma unroll
    for (int i = 0; i < 8; ++i) { acc0[i] = bj0; acc1[i] = bj1; }

    const float* srcs[3] = { x, agg_in, agg_out };
    const float* wms[3]  = { Ws, Wi, Wo };

#pragma unroll
    for (int s = 0; s < 3; ++s) {
        const float4* src4 = reinterpret_cast<const float4*>(srcs[s]);
        const float4* w4   = reinterpret_cast<const float4*>(wms[s]);
        __syncthreads();
#pragma unroll
        for (int it = 0; it < 16; ++it) {
            int gi = t + 256 * it;
            int j = gi >> 5, k4 = gi & 31;
            Wl[j * 32 + (k4 ^ (j & 7))] = w4[gi];
        }
#pragma unroll
        for (int it = 0; it < 4; ++it) {
            int gi = t + 256 * it;
            int m = gi >> 5, k4 = gi & 31;
            int node = base + m;
            float4 v = (node < n) ? src4[(size_t)node * 32 + k4]
                                  : make_float4(0.f, 0.f, 0.f, 0.f);
            Xl[m * 32 + k4] = v;
        }
        __syncthreads();

        const int sw = j0 & 7;
#pragma unroll 8
        for (int k4 = 0; k4 < 32; ++k4) {
            float4 w0 = Wl[j0 * 32 + (k4 ^ sw)];
            float4 w1 = Wl[j1 * 32 + (k4 ^ sw)];
#pragma unroll
            for (int i = 0; i < 8; ++i) {
                float4 xv = Xl[(w + 4 * i) * 32 + k4];
                acc0[i] += xv.x * w0.x + xv.y * w0.y + xv.z * w0.z + xv.w * w0.w;
                acc1[i] += xv.x * w1.x + xv.y * w1.y + xv.z * w1.z + xv.w * w1.w;
            }
        }
    }

    const float g0 = gamma[j0], g1 = gamma[j1];
    const float be0 = beta[j0], be1 = beta[j1];
#pragma unroll
    for (int i = 0; i < 8; ++i) {
        int node = base + w + 4 * i;
        float s  = acc0[i] + acc1[i];
        float ss = acc0[i] * acc0[i] + acc1[i] * acc1[i];
#pragma unroll
        for (int off = 32; off; off >>= 1) {
            s  += __shfl_xor(s, off);
            ss += __shfl_xor(ss, off);
        }
        float mu   = s * (1.0f / D);
        float var  = ss * (1.0f / D) - mu * mu;
        float rstd = rsqrtf(var + 1e-5f);
        if (node < n) {
            float y0 = (acc0[i] - mu) * rstd * g0 + be0;
            float y1 = (acc1[i] - mu) * rstd * g1 + be1;
            out[(size_t)node * D + j0] = fmaxf(y0, 0.f);
            out[(size_t)node * D + j1] = fmaxf(y1, 0.f);
        }
    }
}

extern "C" void kernel_launch(void* const* d_in, const int* in_sizes, int n_in,
                              void* d_out, int out_size, void* d_ws, size_t ws_size,
                              hipStream_t stream) {
    const float* x     = (const float*)d_in[0];
    const int*   ir    = (const int*)  d_in[1];
    const int*   icoln = (const int*)  d_in[2];
    const float* ival  = (const float*)d_in[3];
    const int*   orow  = (const int*)  d_in[4];
    const int*   ocol  = (const int*)  d_in[5];
    const float* oval  = (const float*)d_in[6];
    const float* Ws    = (const float*)d_in[7];
    const float* b     = (const float*)d_in[8];
    const float* Wi    = (const float*)d_in[9];
    const float* Wo    = (const float*)d_in[10];
    const float* gamma = (const float*)d_in[11];
    const float* beta  = (const float*)d_in[12];
    float* out = (float*)d_out;

    // workspace layout
    short*    A       = (short*)d_ws;                      // NPAD x 384 bf16
    short*    Wc      = A + (size_t)NPAD * KA;             // 128 x 384 bf16
    int*      bcnt    = (int*)(Wc + (size_t)128 * KA);
    int*      bbase   = bcnt + NBB;
    int*      bcur    = bbase + NBB;
    int*      row_ptr = bcur + NBB;                        // NBB*64 + 1 entries
    uintptr_t pp      = (uintptr_t)(row_ptr + NBB * 64 + 1);
    pp = (pp + 7) & ~(uintptr_t)7;
    int2*     pairp   = (int2*)pp;                         // NE2 (8B)
    unsigned* pairp2  = (unsigned*)(pairp + NE2);          // NE2 (4B packed)
    size_t need = (size_t)((char*)(pairp2 + NE2) - (char*)d_ws);

    if (ws_size >= need) {
        prep<<<G1 + G2 + G3, 256, 0, stream>>>(x, Ws, Wi, Wo, A, Wc, bcnt);
        bucket_hist<<<128, 1024, 0, stream>>>(ir, orow, bcnt);
        scan_buckets<<<1, 1024, 0, stream>>>(bcnt, bbase, bcur);
        scatter_chunks<<<(NE2 + CHUNK_A - 1) / CHUNK_A, 1024, 0, stream>>>(
            ir, icoln, ival, orow, ocol, oval, bcur, pairp);
        row_sort<<<NBB, 256, 0, stream>>>(bbase, bcnt, pairp, pairp2, row_ptr);
        gather_rows<<<(NT + 3) / 4, 256, 0, stream>>>(row_ptr, pairp2, A);
        gemm_mfma<<<NPAD / GBM, 512, 0, stream>>>(A, Wc, b, gamma, beta, out);
    } else {
        float* agg_in  = (float*)d_ws;
        float* agg_out = agg_in + (size_t)N_NODES * D;
        hipMemsetAsync(d_ws, 0, 2 * (size_t)N_NODES * D * sizeof(float), stream);
        const int eblocks = (N_EDGES * 32 + 255) / 256;
        spmm_scatter<<<eblocks, 256, 0, stream>>>(ir, icoln, ival, x, agg_in, N_EDGES);
        spmm_scatter<<<eblocks, 256, 0, stream>>>(orow, ocol, oval, x, agg_out, N_EDGES);
        const int gblocks = (N_NODES + BM - 1) / BM;
        gemm_ln_relu<<<gblocks, 256, 0, stream>>>(x, agg_in, agg_out, Ws, Wi, Wo,
                                                  b, gamma, beta, out, N_NODES);
    }
}